// Round 4
// baseline (41.949 us; speedup 1.0000x reference)
//
#include <hip/hip_runtime.h>

#define KAPPA 0.276f
#define NTRI 8256        // 128*129/2 packed floats per batch
#define BATCH 1024
#define NBLK 2048        // 2 blocks per batch; 1032 quads each
#define SCALE (1.0f / (128.0f * 1024.0f))   // /trace2(=128), /B for mean

__global__ __launch_bounds__(256) void trace_kernel(const float* __restrict__ net_out,
                                                    const float* __restrict__ U1,
                                                    float* __restrict__ ws) {
    const int bid  = blockIdx.x;          // 2 blocks per batch
    const int b    = bid >> 1;
    const int qoff = (bid & 1) * 1032;    // half-batch quad offset (2064/2)
    const int tid  = threadIdx.x;

    const float* __restrict__  X  = net_out + (size_t)b * NTRI;
    const float4* __restrict__ X4 = (const float4*)X;
    const float* __restrict__  U  = U1 + (size_t)b * 128;

    float part = 0.f;

    for (int m = 0; m < 5; ++m) {
        int t = tid + (m << 8);
        if (t >= 1032) break;             // 1032 = 4*256 + 8
        int qi = qoff + t;
        int j0 = qi << 2;
        float4 v = X4[qi];
        float xs0 = v.x, xs1 = v.y, xs2 = v.z, xs3 = v.w;

        #pragma unroll
        for (int e = 0; e < 4; ++e) {
            int j = j0 + e;
            float x = (e == 0) ? xs0 : (e == 1) ? xs1 : (e == 2) ? xs2 : xs3;

            // row decode: i = floor((sqrt(8j+1)-1)/2) with exact fixup (verified R2)
            float s = sqrtf((float)(8 * j + 1));
            int i = (int)((s - 1.0f) * 0.5f);
            int tri = (i * (i + 1)) >> 1;
            if (tri > j)                 { --i; tri -= i + 1; }
            else if (tri + i + 1 <= j)   { tri += i + 1; ++i; }
            int k = j - tri;

            // in-row hop partners (columns); loads always in-bounds (tri+127 <= 8255)
            int kA = (k + 16) & 127;
            int kB = (k & 0x70) | ((k + 2) & 15);
            float xA = X[tri + kA];
            float xB = X[tri + kB];
            xA = (kA <= i) ? xA : 0.f;    // upper triangle = 0
            xB = (kB <= i) ? xB : 0.f;

            int st = k >> 1;              // lattice site of column k
            float cA = cosf(U[st]);
            float cB = cosf(U[64 + st]);

            float h = cA * xA + cB * xB;
            // part += x*x - 2*kappa*x*h
            part = fmaf(x, fmaf(-2.0f * KAPPA, h, x), part);
        }
    }

    // wave reduce
    #pragma unroll
    for (int off = 32; off > 0; off >>= 1)
        part += __shfl_down(part, off, 64);

    __shared__ float red[4];
    if ((tid & 63) == 0) red[tid >> 6] = part;
    __syncthreads();
    if (tid == 0)
        ws[bid] = red[0] + red[1] + red[2] + red[3];
}

__global__ __launch_bounds__(256) void reduce_kernel(const float* __restrict__ ws,
                                                     float* __restrict__ out) {
    const int tid = threadIdx.x;
    float v = 0.f;
    #pragma unroll
    for (int m = 0; m < NBLK / 256; ++m)
        v += ws[tid + (m << 8)];
    #pragma unroll
    for (int off = 32; off > 0; off >>= 1)
        v += __shfl_down(v, off, 64);
    __shared__ float red[4];
    if ((tid & 63) == 0) red[tid >> 6] = v;
    __syncthreads();
    if (tid == 0)
        out[0] = (red[0] + red[1] + red[2] + red[3]) * SCALE;
}

extern "C" void kernel_launch(void* const* d_in, const int* in_sizes, int n_in,
                              void* d_out, int out_size, void* d_ws, size_t ws_size,
                              hipStream_t stream) {
    const float* net_out = (const float*)d_in[0];  // (1024, 8256) fp32
    const float* U1      = (const float*)d_in[1];  // (1024, 2, 8, 8) fp32
    float* out = (float*)d_out;                    // scalar fp32
    float* ws  = (float*)d_ws;                     // >= NBLK floats

    trace_kernel<<<NBLK, 256, 0, stream>>>(net_out, U1, ws);
    reduce_kernel<<<1, 256, 0, stream>>>(ws, out);
}

// Round 5
// 20.180 us; speedup vs baseline: 2.0788x; 2.0788x over previous
//
#include <hip/hip_runtime.h>

#define KAPPA 0.276f
#define NTRI 8256        // 128*129/2 packed floats per batch
#define BATCH 1024
#define NBLK 2048        // 2 blocks per batch (row classes mod 8)
#define SCALE (1.0f / (128.0f * 1024.0f))   // /trace2(=128), /B for mean

__global__ __launch_bounds__(256) void trace_kernel(const float* __restrict__ net_out,
                                                    const float* __restrict__ U1,
                                                    float* __restrict__ ws) {
    const int bid = blockIdx.x;
    const int b   = bid >> 1;
    const int tid = threadIdx.x;
    const int w   = tid >> 6;                 // wave 0..3
    const int l   = tid & 63;                 // lane owns row elements k=2l, 2l+1
    const int r   = ((bid & 1) << 2) + w;     // row class 0..7: rows r, r+8, ..., r+120

    const float* __restrict__ X = net_out + (size_t)b * NTRI;

    // per-lane loop-invariant coefficients (site of k=2l,2l+1 is exactly l)
    const float cA = -2.0f * KAPPA * cosf(U1[(size_t)b * 128 + l]);
    const float cB = -2.0f * KAPPA * cosf(U1[(size_t)b * 128 + 64 + l]);

    // per-lane loop-invariant partner columns (verified mapping, R1/R3/R4 absmax 0.0)
    const int k0  = 2 * l;
    const int k1  = 2 * l + 1;
    const int kA0 = (k0 + 16) & 127;              // kA1 = kA0 + 1
    const int kA1 = kA0 + 1;
    const int kB0 = (k0 & 0x70) | ((k0 + 2) & 15); // kB1 = kB0 + 1
    const int kB1 = kB0 + 1;

    float sq = 0.f, hA = 0.f, hB = 0.f;
    int i   = r;
    int tri = (r * (r + 1)) >> 1;

    #pragma unroll 4
    for (int t = 0; t < 16; ++t) {
        // all loads in-bounds: tri + 127 <= 8255; beyond-diagonal reads masked below
        float x0 = X[tri + k0];
        float x1 = X[tri + k1];
        float a0 = X[tri + kA0];
        float a1 = X[tri + kA1];
        float b0 = X[tri + kB0];
        float b1 = X[tri + kB1];
        x0 = (k0  <= i) ? x0 : 0.f;
        x1 = (k1  <= i) ? x1 : 0.f;
        a0 = (kA0 <= i) ? a0 : 0.f;
        a1 = (kA1 <= i) ? a1 : 0.f;
        b0 = (kB0 <= i) ? b0 : 0.f;
        b1 = (kB1 <= i) ? b1 : 0.f;
        sq = fmaf(x0, x0, fmaf(x1, x1, sq));
        hA = fmaf(x0, a0, fmaf(x1, a1, hA));
        hB = fmaf(x0, b0, fmaf(x1, b1, hB));
        tri += (i << 3) + 36;     // tri(i+8) - tri(i) = 8i + 36
        i   += 8;
    }

    float val = fmaf(cA, hA, fmaf(cB, hB, sq));

    // wave reduce
    #pragma unroll
    for (int off = 32; off > 0; off >>= 1)
        val += __shfl_down(val, off, 64);

    __shared__ float red[4];
    if (l == 0) red[w] = val;
    __syncthreads();
    if (tid == 0)
        ws[bid] = red[0] + red[1] + red[2] + red[3];
}

__global__ __launch_bounds__(256) void reduce_kernel(const float* __restrict__ ws,
                                                     float* __restrict__ out) {
    const int tid = threadIdx.x;
    float v = 0.f;
    #pragma unroll
    for (int m = 0; m < NBLK / 256; ++m)
        v += ws[tid + (m << 8)];
    #pragma unroll
    for (int off = 32; off > 0; off >>= 1)
        v += __shfl_down(v, off, 64);
    __shared__ float red[4];
    if ((tid & 63) == 0) red[tid >> 6] = v;
    __syncthreads();
    if (tid == 0)
        out[0] = (red[0] + red[1] + red[2] + red[3]) * SCALE;
}

extern "C" void kernel_launch(void* const* d_in, const int* in_sizes, int n_in,
                              void* d_out, int out_size, void* d_ws, size_t ws_size,
                              hipStream_t stream) {
    const float* net_out = (const float*)d_in[0];  // (1024, 8256) fp32
    const float* U1      = (const float*)d_in[1];  // (1024, 2, 8, 8) fp32
    float* out = (float*)d_out;                    // scalar fp32
    float* ws  = (float*)d_ws;                     // >= NBLK floats

    trace_kernel<<<NBLK, 256, 0, stream>>>(net_out, U1, ws);
    reduce_kernel<<<1, 256, 0, stream>>>(ws, out);
}

// Round 6
// 18.134 us; speedup vs baseline: 2.3133x; 1.1129x over previous
//
#include <hip/hip_runtime.h>

#define KAPPA 0.276f
#define NTRI 8256        // 128*129/2 packed floats per batch
#define BATCH 1024
#define NBLK 2048        // 2 blocks per batch (row classes mod 8)
#define SCALE (1.0f / (128.0f * 1024.0f))   // /trace2(=128), /B for mean

__global__ __launch_bounds__(256) void trace_kernel(const float* __restrict__ net_out,
                                                    const float* __restrict__ U1,
                                                    float* __restrict__ ws) {
    const int bid = blockIdx.x;
    const int b   = bid >> 1;
    const int tid = threadIdx.x;
    const int w   = tid >> 6;                 // wave 0..3
    const int l   = tid & 63;                 // lane owns elements k=l and k=l+64 of each row
    const int r   = ((bid & 1) << 2) + w;     // row class 0..7: rows r, r+8, ..., r+120

    const float* __restrict__ X = net_out + (size_t)b * NTRI;
    const float* __restrict__ U = U1 + (size_t)b * 128;

    // loop-invariant per-lane partner offsets (element index within row)
    const int kxl = l;                          // low-half own element
    const int kal = l + 16;                     // (l+16)&127, no wrap for l<=63
    const int kbl = (l & 0x70) | ((l + 2) & 15);
    const int kxh = l + 64;                     // high-half own element
    const int kah = (l + 80) & 127;             // wraps for l>=48
    const int kbh = ((l + 64) & 0x70) | ((l + 66) & 15);

    float sq = 0.f, hAl = 0.f, hBl = 0.f, hAh = 0.f, hBh = 0.f;

    // ---- rows i = r .. r+56 : only low half (k <= i < 64) ----
    {
        int i   = r;
        int o   = (r * (r + 1)) >> 1;
        #pragma unroll
        for (int t = 0; t < 8; ++t) {
            const float* __restrict__ R = X + o;
            float x = R[kxl];
            float a = R[kal];
            float bb = R[kbl];
            x  = (kxl <= i) ? x  : 0.f;
            a  = (kal <= i) ? a  : 0.f;
            bb = (kbl <= i) ? bb : 0.f;
            sq  = fmaf(x, x,  sq);
            hAl = fmaf(x, a,  hAl);
            hBl = fmaf(x, bb, hBl);
            o += (i << 3) + 36;   // tri(i+8)-tri(i)
            i += 8;
        }
    }
    // ---- rows i = r+64 .. r+120 : both halves ----
    {
        int i   = r + 64;
        int o   = (i * (i + 1)) >> 1;
        #pragma unroll
        for (int t = 0; t < 8; ++t) {
            const float* __restrict__ R = X + o;
            float x = R[kxl];            // low half: k=l <= 63 < i, always valid
            float a = R[kal];
            float bb = R[kbl];
            a  = (kal <= i) ? a  : 0.f;  // kal up to 79 can exceed i (i>=64)
            // kbl <= 63 < i: always valid
            sq  = fmaf(x, x,  sq);
            hAl = fmaf(x, a,  hAl);
            hBl = fmaf(x, bb, hBl);

            float xh = R[kxh];
            float ah = R[kah];
            float bh = R[kbh];
            xh = (kxh <= i) ? xh : 0.f;
            ah = (kah <= i) ? ah : 0.f;  // wrapped kah (<16) always passes
            bh = (kbh <= i) ? bh : 0.f;
            sq  = fmaf(xh, xh, sq);
            hAh = fmaf(xh, ah, hAh);
            hBh = fmaf(xh, bh, hBh);

            o += (i << 3) + 36;
            i += 8;
        }
    }

    // per-lane loop-invariant coefficients (site of element k is k>>1)
    const float m2k  = -2.0f * KAPPA;
    const float cAl = m2k * cosf(U[(l >> 1)]);
    const float cAh = m2k * cosf(U[32 + (l >> 1)]);
    const float cBl = m2k * cosf(U[64 + (l >> 1)]);
    const float cBh = m2k * cosf(U[96 + (l >> 1)]);

    float val = sq + cAl * hAl + cAh * hAh + cBl * hBl + cBh * hBh;

    // wave reduce
    #pragma unroll
    for (int off = 32; off > 0; off >>= 1)
        val += __shfl_down(val, off, 64);

    __shared__ float red[4];
    if (l == 0) red[w] = val;
    __syncthreads();
    if (tid == 0)
        ws[bid] = red[0] + red[1] + red[2] + red[3];
}

__global__ __launch_bounds__(256) void reduce_kernel(const float* __restrict__ ws,
                                                     float* __restrict__ out) {
    const int tid = threadIdx.x;
    float v = 0.f;
    #pragma unroll
    for (int m = 0; m < NBLK / 256; ++m)
        v += ws[tid + (m << 8)];
    #pragma unroll
    for (int off = 32; off > 0; off >>= 1)
        v += __shfl_down(v, off, 64);
    __shared__ float red[4];
    if ((tid & 63) == 0) red[tid >> 6] = v;
    __syncthreads();
    if (tid == 0)
        out[0] = (red[0] + red[1] + red[2] + red[3]) * SCALE;
}

extern "C" void kernel_launch(void* const* d_in, const int* in_sizes, int n_in,
                              void* d_out, int out_size, void* d_ws, size_t ws_size,
                              hipStream_t stream) {
    const float* net_out = (const float*)d_in[0];  // (1024, 8256) fp32
    const float* U1      = (const float*)d_in[1];  // (1024, 2, 8, 8) fp32
    float* out = (float*)d_out;                    // scalar fp32
    float* ws  = (float*)d_ws;                     // >= NBLK floats

    trace_kernel<<<NBLK, 256, 0, stream>>>(net_out, U1, ws);
    reduce_kernel<<<1, 256, 0, stream>>>(ws, out);
}